// Round 12
// baseline (759.667 us; speedup 1.0000x reference)
//
#include <hip/hip_runtime.h>
#include <hip/hip_fp16.h>

#define BB 512
#define TT 512
#define EE 100
#define HH 40
#define GG 120   // 3*HH
#define TC 64    // timesteps per chunk
#define NC 8     // chunks

typedef _Float16 h2_t __attribute__((ext_vector_type(2)));

__device__ __forceinline__ float fdot2_(h2_t a, h2_t b, float c) {
    return __builtin_amdgcn_fdot2(a, b, c, false);
}
__device__ __forceinline__ h2_t pack2_(float x, float y) {
    h2_t r; r[0] = (_Float16)x; r[1] = (_Float16)y; return r;
}
__device__ __forceinline__ float sigmoid_(float x) {
    return 1.0f / (1.0f + __expf(-x));
}
__device__ __forceinline__ float tanhfast_(float x) {
    float e = __expf(2.0f * x);
    return 1.0f - 2.0f / (e + 1.0f);
}

// Round-12 = r9 + wave-private LDS staging of gx (the untested matrix cell:
// LDS-staged gx x SINGLE chain/wave). Ledger: r7 showed ~700-900cyc/step of
// non-issue stall that a 2nd chain absorbs; only the 3 scattered gx global
// loads (far-L2/L3, ~500-900cyc, 1-step lookahead ~400cyc compute) match.
// Each scan wave copies its TC x 120 gx slice to LDS once (15 float4/lane,
// coalesced, in-order DS -> no barrier); per-step prefetch = 3 ds_read_u16
// (~120cyc, fully covered). GEMM = r9's 64-col tile (r11's 128-col added
// bank conflicts, no win). Kept: setprio 3/0, length-ranges, early-out,
// fp16 Whh in 60 resident VGPRs under launch_bounds(256,2), gx dbuf.
template<int K, bool GATHER>
__global__ __launch_bounds__(256, 2) void fused_kernel(
    const int cg, const int cs, const int nScan,
    const int* __restrict__ text, const float* __restrict__ emb,
    const __half* __restrict__ Xh,
    const float* __restrict__ Wf, const float* __restrict__ bf,
    const float* __restrict__ Wb, const float* __restrict__ bb,
    __half* __restrict__ gxW, const __half* __restrict__ gxR,
    const float* __restrict__ WhhF, const float* __restrict__ bhhF,
    const float* __restrict__ WhhB, const float* __restrict__ bhhB,
    const int* __restrict__ lens,
    __half* __restrict__ out0,
    float* __restrict__ hcar, float* __restrict__ hlast,
    float* __restrict__ sumb, float* __restrict__ maxb)
{
    constexpr int K2 = K / 2;
    // union: scan = hsh(384B) + 4 x 15360B gx slices; gemm = Xs2 + Ws2
    __shared__ __align__(16) char smem[384 + 4 * TC * GG * 2];
    const int tid = threadIdx.x;

    if ((int)blockIdx.x < nScan) {
        // ============ scan: one wave = one (batch,dir) chain ============
        __builtin_amdgcn_s_setprio(3);
        const int wave = tid >> 6, lane = tid & 63;
        const int chain = blockIdx.x * 4 + wave;   // 0..1023
        const int dir = chain >> 9;
        const int b   = chain & (BB - 1);
        const int len = lens[b];
        const int chunk = dir ? (NC - 1 - cs) : cs;
        const int tbase = chunk * TC;

        // executed step range: all executed steps have t < len
        int sBeg, sEnd;
        if (dir == 0) { sBeg = 0; sEnd = min(TC, max(0, len - tbase)); }
        else          { sBeg = max(0, tbase + TC - len); sEnd = TC; }

        // stage this chain's gx slice into wave-private LDS (no barrier:
        // DS ops are in-order within the wave)
        _Float16* gxs = (_Float16*)(smem + 384) + wave * (TC * GG);
        const size_t gxRow = ((size_t)dir * BB + b) * TC;
        if (sBeg < sEnd) {
            float4* dst = (float4*)gxs;
            const float4* src = (const float4*)(gxR + gxRow * GG);
            #pragma unroll
            for (int i = 0; i < (TC * GG * 2) / (16 * 64); ++i)   // 15
                dst[i * 64 + lane] = src[i * 64 + lane];
        }
        if (lane >= HH) return;
        const int j = lane;

        const float* Whh = dir ? WhhB : WhhF;
        const float* bhh = dir ? bhhB : bhhF;
        // Whh rows {j,40+j,80+j} packed half2: 60 VGPRs, resident
        h2_t Wr[HH/2], Wz[HH/2], Wn[HH/2];
        {
            const float4* r4 = (const float4*)(Whh + (size_t)(0*HH + j) * HH);
            const float4* z4 = (const float4*)(Whh + (size_t)(1*HH + j) * HH);
            const float4* n4 = (const float4*)(Whh + (size_t)(2*HH + j) * HH);
            #pragma unroll
            for (int q = 0; q < HH/4; ++q) {
                float4 v;
                v = r4[q]; Wr[2*q] = pack2_(v.x,v.y); Wr[2*q+1] = pack2_(v.z,v.w);
                v = z4[q]; Wz[2*q] = pack2_(v.x,v.y); Wz[2*q+1] = pack2_(v.z,v.w);
                v = n4[q]; Wn[2*q] = pack2_(v.x,v.y); Wn[2*q+1] = pack2_(v.z,v.w);
            }
        }
        const float br = bhh[j], bz = bhh[HH + j], bn = bhh[2*HH + j];

        _Float16* hshw = (_Float16*)smem + wave * 48;
        float h = (cs == 0) ? 0.0f : hcar[(size_t)(dir * BB + b) * HH + j];
        hshw[j] = (_Float16)h;
        float psum = 0.0f, pmax = -3.4e38f;

        // current-step gx regs from LDS slice
        float rC = 0.f, zC = 0.f, nC = 0.f;
        if (sBeg < sEnd) {
            const int tl0 = dir ? (TC - 1 - sBeg) : sBeg;
            rC = (float)gxs[tl0*GG + j];
            zC = (float)gxs[tl0*GG + HH + j];
            nC = (float)gxs[tl0*GG + 2*HH + j];
        }

        const float4* h4 = (const float4*)hshw;
        for (int s = sBeg; s < sEnd; ++s) {
            const int tloc = dir ? (TC - 1 - s) : s;
            const int t = tbase + tloc;
            float rN = 0.f, zN = 0.f, nN = 0.f;
            if (s + 1 < sEnd) {   // prefetch next step's gx from LDS
                const int tn = dir ? (TC - 2 - s) : (s + 1);
                rN = (float)gxs[tn*GG + j];
                zN = (float)gxs[tn*GG + HH + j];
                nN = (float)gxs[tn*GG + 2*HH + j];
            }
            // GEMV: 60 dot2, two partial accumulators per gate
            float r0 = br, r1 = 0.f, z0 = bz, z1 = 0.f, n0 = bn, n1 = 0.f;
            #pragma unroll
            for (int q = 0; q < 5; ++q) {
                union { float4 f; h2_t h[4]; } u;
                u.f = h4[q];
                r0 = fdot2_(Wr[4*q+0], u.h[0], r0);
                z0 = fdot2_(Wz[4*q+0], u.h[0], z0);
                n0 = fdot2_(Wn[4*q+0], u.h[0], n0);
                r1 = fdot2_(Wr[4*q+1], u.h[1], r1);
                z1 = fdot2_(Wz[4*q+1], u.h[1], z1);
                n1 = fdot2_(Wn[4*q+1], u.h[1], n1);
                r0 = fdot2_(Wr[4*q+2], u.h[2], r0);
                z0 = fdot2_(Wz[4*q+2], u.h[2], z0);
                n0 = fdot2_(Wn[4*q+2], u.h[2], n0);
                r1 = fdot2_(Wr[4*q+3], u.h[3], r1);
                z1 = fdot2_(Wz[4*q+3], u.h[3], z1);
                n1 = fdot2_(Wn[4*q+3], u.h[3], n1);
            }
            const float rr = sigmoid_(rC + r0 + r1);
            const float zz = sigmoid_(zC + z0 + z1);
            const float nn = tanhfast_(nC + rr * (n0 + n1));
            const float hn = fmaf(zz, h - nn, nn);   // (1-z)n + z h
            h = hn;
            hshw[j] = (_Float16)h;    // broadcast for next step
            if (GATHER) {  // layer 0: materialize out0 fp16 (valid t only)
                out0[((size_t)b * TT + t) * (2*HH) + dir*HH + j] = __float2half(hn);
            } else {       // layer 1: fused pooling (valid t only)
                psum += hn;
                pmax = fmaxf(pmax, hn);
            }
            rC = rN; zC = zN; nC = nN;
        }
        hcar[(size_t)(dir * BB + b) * HH + j] = h;
        const int layer = GATHER ? 0 : 1;
        if (cs == NC - 1)
            hlast[((size_t)(layer * 2 + dir) * BB + b) * HH + j] = h;
        if (!GATHER) {
            const size_t pi = (size_t)b * (2*HH) + dir*HH + j;
            if (cs == 0) { sumb[pi] = psum;  maxb[pi] = pmax; }
            else         { sumb[pi] += psum; maxb[pi] = fmaxf(maxb[pi], pmax); }
        }
        return;
    }

    // ================= gemm (fp16 dot2, r9 tile), prio 0 =================
    __builtin_amdgcn_s_setprio(0);
    h2_t* Xs2 = (h2_t*)smem;                     // [K2][64]
    h2_t* Ws2 = (h2_t*)(smem + K2 * 64 * 4);     // [K2][64]
    const int gid = blockIdx.x - nScan;
    const int b   = gid & (BB - 1);
    const int ct  = (gid >> 9) & 1;
    const int dir = gid >> 10;
    const int chunk = dir ? (NC - 1 - cg) : cg;
    const int tbase = chunk * TC;
    if (tbase >= lens[b]) return;   // tile fully past len: gx never read
    const float* W    = dir ? Wb : Wf;
    const float* bias = dir ? bb : bf;
    const int c0 = ct * 64;

    if (GATHER) {
        constexpr int KQ = K / 4;
        for (int idx = tid; idx < 64 * KQ; idx += 256) {
            const int r = idx & 63, q = idx >> 6;
            const int tok = text[b * TT + tbase + r];
            const float4 v = ((const float4*)emb)[(size_t)tok * KQ + q];
            Xs2[(2*q+0)*64 + r] = pack2_(v.x, v.y);
            Xs2[(2*q+1)*64 + r] = pack2_(v.z, v.w);
        }
    } else {
        constexpr int KQ8 = K / 8;
        for (int idx = tid; idx < 64 * KQ8; idx += 256) {
            const int r = idx & 63, q = idx >> 6;
            union { float4 f; h2_t h[4]; } u;
            u.f = ((const float4*)Xh)[((size_t)b * TT + tbase + r) * KQ8 + q];
            #pragma unroll
            for (int i2 = 0; i2 < 4; ++i2)
                Xs2[(4*q + i2)*64 + r] = u.h[i2];
        }
    }
    {
        constexpr int KQ = K / 4;
        for (int idx = tid; idx < 64 * KQ; idx += 256) {
            const int c = idx & 63, q = idx >> 6;
            float4 v = make_float4(0.f,0.f,0.f,0.f);
            if (c0 + c < GG) v = ((const float4*)W)[(size_t)(c0 + c) * KQ + q];
            Ws2[(2*q+0)*64 + c] = pack2_(v.x, v.y);
            Ws2[(2*q+1)*64 + c] = pack2_(v.z, v.w);
        }
    }
    __syncthreads();

    const int tx = tid & 15, ty = tid >> 4;
    float acc[4][4] = {};
    #pragma unroll 2
    for (int k2 = 0; k2 < K2; ++k2) {
        union { float4 f; h2_t h[4]; } xa, wv;
        xa.f = *(const float4*)(Xs2 + k2*64 + (ty << 2));
        wv.f = *(const float4*)(Ws2 + k2*64 + (tx << 2));
        #pragma unroll
        for (int i = 0; i < 4; ++i)
            #pragma unroll
            for (int j2 = 0; j2 < 4; ++j2)
                acc[i][j2] = fdot2_(xa.h[i], wv.h[j2], acc[i][j2]);
    }

    const int c = c0 + (tx << 2);
    if (c < GG) {
        const float b0v = bias[c], b1v = bias[c+1], b2v = bias[c+2], b3v = bias[c+3];
        const size_t rowB = ((size_t)dir * BB + b) * TC;
        #pragma unroll
        for (int i = 0; i < 4; ++i) {
            const int tloc = (ty << 2) + i;
            union { float2 f; __half2 h[2]; } u;
            u.h[0] = __floats2half2_rn(acc[i][0] + b0v, acc[i][1] + b1v);
            u.h[1] = __floats2half2_rn(acc[i][2] + b2v, acc[i][3] + b3v);
            *(float2*)(gxW + (rowB + tloc) * GG + c) = u.f;
        }
    }
}

// pool_cat = [hb1, hf1, hb0, hf0, avg(80), max(80)] -> fc1(128) -> lrelu -> fc2(1)
__global__ __launch_bounds__(128) void fc_kernel(
    const float* __restrict__ hlast, const float* __restrict__ sumb,
    const float* __restrict__ maxb, const int* __restrict__ lens,
    const float* __restrict__ fc1W, const float* __restrict__ fc1b,
    const float* __restrict__ fc2W, const float* __restrict__ fc2b,
    float* __restrict__ out)
{
    __shared__ float pool[8 * HH];
    __shared__ float red[128];
    const int b = blockIdx.x, tid = threadIdx.x;
    if (tid < HH) {
        pool[tid]        = hlast[(size_t)(3*BB + b) * HH + tid]; // hb1
        pool[HH + tid]   = hlast[(size_t)(2*BB + b) * HH + tid]; // hf1
        pool[2*HH + tid] = hlast[(size_t)(1*BB + b) * HH + tid]; // hb0
        pool[3*HH + tid] = hlast[(size_t)(0*BB + b) * HH + tid]; // hf0
    }
    const float invLen = 1.0f / (float)lens[b];
    if (tid < 2*HH) {
        pool[4*HH + tid] = sumb[(size_t)b * 2*HH + tid] * invLen;
        pool[6*HH + tid] = maxb[(size_t)b * 2*HH + tid];
    }
    __syncthreads();
    float acc = fc1b[tid];
    for (int k = 0; k < 8*HH; ++k)
        acc = fmaf(pool[k], fc1W[(size_t)tid * (8*HH) + k], acc);
    float v = (acc >= 0.0f) ? acc : 0.01f * acc;
    red[tid] = v * fc2W[tid];
    __syncthreads();
    for (int s = 64; s > 0; s >>= 1) {
        if (tid < s) red[tid] += red[tid + s];
        __syncthreads();
    }
    if (tid == 0) out[b] = red[0] + fc2b[0];
}

extern "C" void kernel_launch(void* const* d_in, const int* in_sizes, int n_in,
                              void* d_out, int out_size, void* d_ws, size_t ws_size,
                              hipStream_t stream) {
    const int*   text  = (const int*)d_in[0];
    const int*   lens  = (const int*)d_in[1];
    const float* emb   = (const float*)d_in[2];
    const float* Wih0f = (const float*)d_in[3];
    const float* Whh0f = (const float*)d_in[4];
    const float* bih0f = (const float*)d_in[5];
    const float* bhh0f = (const float*)d_in[6];
    const float* Wih0b = (const float*)d_in[7];
    const float* Whh0b = (const float*)d_in[8];
    const float* bih0b = (const float*)d_in[9];
    const float* bhh0b = (const float*)d_in[10];
    const float* Wih1f = (const float*)d_in[11];
    const float* Whh1f = (const float*)d_in[12];
    const float* bih1f = (const float*)d_in[13];
    const float* bhh1f = (const float*)d_in[14];
    const float* Wih1b = (const float*)d_in[15];
    const float* Whh1b = (const float*)d_in[16];
    const float* bih1b = (const float*)d_in[17];
    const float* bhh1b = (const float*)d_in[18];
    const float* fc1W  = (const float*)d_in[19];
    const float* fc1b  = (const float*)d_in[20];
    const float* fc2W  = (const float*)d_in[21];
    const float* fc2b  = (const float*)d_in[22];
    float* out = (float*)d_out;

    // ws: gx double-buffer fp16 (2 x 15.73MB) | out0 fp16 (41.94MB) | small
    char* p = (char*)d_ws;
    const size_t gxB = (size_t)2 * BB * TC * GG * sizeof(__half);
    __half* gxb0  = (__half*)p;  p += gxB;
    __half* gxb1  = (__half*)p;  p += gxB;
    __half* out0  = (__half*)p;  p += (size_t)BB * TT * 2 * HH * sizeof(__half);
    float*  hcar  = (float*)p;   p += (size_t)2 * BB * HH * sizeof(float);
    float*  hlast = (float*)p;   p += (size_t)4 * BB * HH * sizeof(float);
    float*  sumb  = (float*)p;   p += (size_t)BB * 2 * HH * sizeof(float);
    float*  maxb  = (float*)p;
    __half* gxb[2] = { gxb0, gxb1 };

    const int NG = BB * 2 * 2;   // 2048 gemm blocks
    const int NS = 256;          // 1024 chains / 4 waves per block

    // ---- layer 0 ----
    fused_kernel<EE, true><<<NG, 256, 0, stream>>>(0, 0, 0,
        text, emb, nullptr, Wih0f, bih0f, Wih0b, bih0b,
        gxb[0], gxb[0], Whh0f, bhh0f, Whh0b, bhh0b,
        lens, out0, hcar, hlast, sumb, maxb);
    for (int ci = 1; ci < NC; ++ci)
        fused_kernel<EE, true><<<NS + NG, 256, 0, stream>>>(ci, ci - 1, NS,
            text, emb, nullptr, Wih0f, bih0f, Wih0b, bih0b,
            gxb[ci & 1], gxb[(ci - 1) & 1], Whh0f, bhh0f, Whh0b, bhh0b,
            lens, out0, hcar, hlast, sumb, maxb);
    fused_kernel<EE, true><<<NS, 256, 0, stream>>>(0, NC - 1, NS,
        text, emb, nullptr, Wih0f, bih0f, Wih0b, bih0b,
        gxb[0], gxb[(NC - 1) & 1], Whh0f, bhh0f, Whh0b, bhh0b,
        lens, out0, hcar, hlast, sumb, maxb);

    // ---- layer 1 ----
    fused_kernel<2*HH, false><<<NG, 256, 0, stream>>>(0, 0, 0,
        text, emb, out0, Wih1f, bih1f, Wih1b, bih1b,
        gxb[0], gxb[0], Whh1f, bhh1f, Whh1b, bhh1b,
        lens, out0, hcar, hlast, sumb, maxb);
    for (int ci = 1; ci < NC; ++ci)
        fused_kernel<2*HH, false><<<NS + NG, 256, 0, stream>>>(ci, ci - 1, NS,
            text, emb, out0, Wih1f, bih1f, Wih1b, bih1b,
            gxb[ci & 1], gxb[(ci - 1) & 1], Whh1f, bhh1f, Whh1b, bhh1b,
            lens, out0, hcar, hlast, sumb, maxb);
    fused_kernel<2*HH, false><<<NS, 256, 0, stream>>>(0, NC - 1, NS,
        text, emb, out0, Wih1f, bih1f, Wih1b, bih1b,
        gxb[0], gxb[(NC - 1) & 1], Whh1f, bhh1f, Whh1b, bhh1b,
        lens, out0, hcar, hlast, sumb, maxb);

    // ---- head ----
    fc_kernel<<<BB, 128, 0, stream>>>(hlast, sumb, maxb, lens,
        fc1W, fc1b, fc2W, fc2b, out);
}